// Round 8
// baseline (195.719 us; speedup 1.0000x reference)
//
#include <hip/hip_runtime.h>
#include <hip/hip_bf16.h>
#include <math.h>

#define OUT0   2097152      // 4*1024*512 (output 0 size)
#define SP_EPS 1e-7f
#define CEXP   0.18033688011112042f   // 0.125 * log2(e): exp(s/8) == exp2(s*CEXP)

typedef __attribute__((ext_vector_type(8))) short bf16x8;
typedef __attribute__((ext_vector_type(4))) float f32x4;

// ---------------- bf16 split helpers (RN-to-nearest-even) ------------------
__device__ __forceinline__ unsigned short f2bf(float f) {
  unsigned int b = __float_as_uint(f);
  return (unsigned short)((b + 0x7fffu + ((b >> 16) & 1u)) >> 16);
}
__device__ __forceinline__ float bf2f(unsigned short u) {
  return __uint_as_float(((unsigned int)u) << 16);
}

// merge two sorted-desc 6-lists (in a[], b[]) -> top-6 of union, sorted desc, into a[]
__device__ __forceinline__ void merge6(float a[6], const float b[6]) {
  float m0 = fmaxf(a[0], b[5]), m1 = fmaxf(a[1], b[4]), m2 = fmaxf(a[2], b[3]),
        m3 = fmaxf(a[3], b[2]), m4 = fmaxf(a[4], b[1]), m5 = fmaxf(a[5], b[0]);
  float x;
  x = fmaxf(m0, m3); m3 = fminf(m0, m3); m0 = x;
  x = fmaxf(m1, m4); m4 = fminf(m1, m4); m1 = x;
  x = fmaxf(m2, m5); m5 = fminf(m2, m5); m2 = x;
  x = fmaxf(m0, m1); m1 = fminf(m0, m1); m0 = x;
  x = fmaxf(m0, m2); m2 = fminf(m0, m2); m0 = x;
  x = fmaxf(m1, m2); m2 = fminf(m1, m2); m1 = x;
  x = fmaxf(m3, m4); m4 = fminf(m3, m4); m3 = x;
  x = fmaxf(m3, m5); m5 = fminf(m3, m5); m3 = x;
  x = fmaxf(m4, m5); m5 = fminf(m4, m5); m4 = x;
  a[0] = m0; a[1] = m1; a[2] = m2; a[3] = m3; a[4] = m4; a[5] = m5;
}

// ---------------- kernel 0: split-convert up to 3 weight matrices ----------
__global__ __launch_bounds__(256) void convW_kernel(
    const float* __restrict__ w0, const float* __restrict__ w1,
    const float* __restrict__ w2, unsigned short* __restrict__ dst)
{
  const int z = blockIdx.z;
  const float* src = (z == 0) ? w0 : (z == 1) ? w1 : w2;
  unsigned short* hi = dst + (size_t)z * (1u << 19);
  unsigned short* lo = hi + (1u << 18);
  const int i = (blockIdx.x * 256 + threadIdx.x) * 4;
  const float4 x = *(const float4*)(src + i);
  ushort4 h, l;
  h.x = f2bf(x.x); l.x = f2bf(x.x - bf2f(h.x));
  h.y = f2bf(x.y); l.y = f2bf(x.y - bf2f(h.y));
  h.z = f2bf(x.z); l.z = f2bf(x.z - bf2f(h.z));
  h.w = f2bf(x.w); l.w = f2bf(x.w - bf2f(h.w));
  *(ushort4*)(hi + i) = h;
  *(ushort4*)(lo + i) = l;
}

// ---------------- kernel 1: QKV projection via split-bf16 MFMA -------------
__global__ __launch_bounds__(256) void qkv_mfma_kernel(
    const float* __restrict__ q, const float* __restrict__ k, const float* __restrict__ v,
    const unsigned short* __restrict__ Wsplit,
    const float* __restrict__ bq, const float* __restrict__ bk, const float* __restrict__ bv,
    unsigned short* __restrict__ qhh, unsigned short* __restrict__ qhl,
    unsigned short* __restrict__ khh, unsigned short* __restrict__ khl,
    float* __restrict__ vh)
{
  __shared__ short Ash[64 * 64], Asl[64 * 64];
  __shared__ short Bsh[128 * 64], Bsl[128 * 64];
  const int z = blockIdx.z;
  const float* A = (z == 0) ? q : (z == 1) ? k : v;
  const unsigned short* Wh = Wsplit + (size_t)z * (1u << 19);
  const unsigned short* Wl = Wh + (1u << 18);
  const float* bias = (z == 0) ? bq : (z == 1) ? bk : bv;
  const int r0 = blockIdx.x * 64, n0 = blockIdx.y * 128;
  const int tid = threadIdx.x, lane = tid & 63, w = tid >> 6;
  const int wr = w >> 1, wc = w & 1;
  const int l15 = lane & 15, l4 = lane >> 4;

  f32x4 acc[2][4];
#pragma unroll
  for (int a = 0; a < 2; ++a)
#pragma unroll
    for (int b = 0; b < 4; ++b) acc[a][b] = (f32x4){0.f, 0.f, 0.f, 0.f};

  for (int kt = 0; kt < 8; ++kt) {
    __syncthreads();
#pragma unroll
    for (int p = 0; p < 2; ++p) {
      const int c = tid + p * 256, row = c >> 3, k8 = (c & 7) * 8;
      const float4 x0 = *(const float4*)(A + (size_t)(r0 + row) * 512 + kt * 64 + k8);
      const float4 x1 = *(const float4*)(A + (size_t)(r0 + row) * 512 + kt * 64 + k8 + 4);
      bf16x8 hv, lv;
      const float xs[8] = {x0.x, x0.y, x0.z, x0.w, x1.x, x1.y, x1.z, x1.w};
#pragma unroll
      for (int j = 0; j < 8; ++j) {
        const unsigned short h = f2bf(xs[j]);
        hv[j] = (short)h; lv[j] = (short)f2bf(xs[j] - bf2f(h));
      }
      const int si = row * 64 + (k8 ^ ((row & 7) << 3));
      *(bf16x8*)&Ash[si] = hv; *(bf16x8*)&Asl[si] = lv;
    }
#pragma unroll
    for (int p = 0; p < 4; ++p) {
      const int c = tid + p * 256, row = c >> 3, k8 = (c & 7) * 8;
      const size_t go = (size_t)(n0 + row) * 512 + kt * 64 + k8;
      const int si = row * 64 + (k8 ^ ((row & 7) << 3));
      *(bf16x8*)&Bsh[si] = *(const bf16x8*)(Wh + go);
      *(bf16x8*)&Bsl[si] = *(const bf16x8*)(Wl + go);
    }
    __syncthreads();
#pragma unroll
    for (int kf = 0; kf < 2; ++kf) {
      const int kb = kf * 32 + l4 * 8;
      bf16x8 ah[2], al2[2];
#pragma unroll
      for (int rb = 0; rb < 2; ++rb) {
        const int ar = wr * 32 + rb * 16 + l15;
        const int si = ar * 64 + (kb ^ ((ar & 7) << 3));
        ah[rb] = *(bf16x8*)&Ash[si]; al2[rb] = *(bf16x8*)&Asl[si];
      }
#pragma unroll
      for (int cb = 0; cb < 4; ++cb) {
        const int br = wc * 64 + cb * 16 + l15;
        const int si = br * 64 + (kb ^ ((br & 7) << 3));
        const bf16x8 bh = *(bf16x8*)&Bsh[si];
        const bf16x8 bl = *(bf16x8*)&Bsl[si];
#pragma unroll
        for (int rb = 0; rb < 2; ++rb) {
          acc[rb][cb] = __builtin_amdgcn_mfma_f32_16x16x32_bf16(al2[rb], bh, acc[rb][cb], 0, 0, 0);
          acc[rb][cb] = __builtin_amdgcn_mfma_f32_16x16x32_bf16(ah[rb], bl, acc[rb][cb], 0, 0, 0);
          acc[rb][cb] = __builtin_amdgcn_mfma_f32_16x16x32_bf16(ah[rb], bh, acc[rb][cb], 0, 0, 0);
        }
      }
    }
  }
  unsigned short* H = (z == 0) ? qhh : khh;
  unsigned short* L = (z == 0) ? qhl : khl;
#pragma unroll
  for (int cb = 0; cb < 4; ++cb) {
    const int col = n0 + wc * 64 + cb * 16 + l15;
    const float bia = bias[col];
    const int h = col >> 6, d = col & 63;
#pragma unroll
    for (int rb = 0; rb < 2; ++rb)
#pragma unroll
      for (int ri = 0; ri < 4; ++ri) {
        const int row = r0 + wr * 32 + rb * 16 + l4 * 4 + ri;
        const int b = row >> 10, ll = row & 1023;
        const size_t idx = ((size_t)(h * 4 + b) << 16) + (ll << 6) + d;
        const float val = acc[rb][cb][ri] + bia;
        if (z == 2) {
          vh[idx] = val;
        } else {
          const unsigned short hv = f2bf(val);
          H[idx] = hv;
          L[idx] = f2bf(val - bf2f(hv));
        }
      }
  }
}

// ---------------- score tile helper (must be bit-identical in both passes) -
__device__ __forceinline__ f32x4 score_tile(
    const bf16x8* qh8, const bf16x8* ql8,
    const unsigned short* __restrict__ khh, const unsigned short* __restrict__ khl,
    size_t ka)
{
  const bf16x8 kh0 = *(const bf16x8*)(khh + ka);
  const bf16x8 kl0 = *(const bf16x8*)(khl + ka);
  const bf16x8 kh1 = *(const bf16x8*)(khh + ka + 32);
  const bf16x8 kl1 = *(const bf16x8*)(khl + ka + 32);
  f32x4 a0 = (f32x4){0.f, 0.f, 0.f, 0.f};
  f32x4 a1 = (f32x4){0.f, 0.f, 0.f, 0.f};
  a0 = __builtin_amdgcn_mfma_f32_16x16x32_bf16(ql8[0], kh0, a0, 0, 0, 0);
  a0 = __builtin_amdgcn_mfma_f32_16x16x32_bf16(qh8[0], kl0, a0, 0, 0, 0);
  a0 = __builtin_amdgcn_mfma_f32_16x16x32_bf16(qh8[0], kh0, a0, 0, 0, 0);
  a1 = __builtin_amdgcn_mfma_f32_16x16x32_bf16(ql8[1], kh1, a1, 0, 0, 0);
  a1 = __builtin_amdgcn_mfma_f32_16x16x32_bf16(qh8[1], kl1, a1, 0, 0, 0);
  a1 = __builtin_amdgcn_mfma_f32_16x16x32_bf16(qh8[1], kh1, a1, 0, 0, 0);
  return a0 + a1;
}

// ---------------- kernel 2: sparse attention, two-sweep, wave-independent --
// Block = 16 q-rows of one bh; 4 waves, wave w owns kv quarter [w*256,(w+1)*256).
// Pass 1 (no barriers): 16 tiles, 6 MFMA each, per-lane {Z-sum, top6 of raw
//   scores} (no max-subtraction: u = exp2(s*CEXP) is overflow-safe here).
// Merge: intra-wave butterfly over 16 row-lanes, then cross-wave via LDS.
// Pass 2: recompute scores bit-identically, write FULL attn rows (exact 0s
//   for non-survivors -> no zerofill kernel), collect <=5 survivors/quarter,
//   then PV + out_full hi/lo split write.
__global__ __launch_bounds__(256) void sparse_attn_kernel(
    const unsigned short* __restrict__ qhh, const unsigned short* __restrict__ qhl,
    const unsigned short* __restrict__ khh, const unsigned short* __restrict__ khl,
    const float* __restrict__ vh, float* __restrict__ attn,
    unsigned short* __restrict__ ofhi, unsigned short* __restrict__ oflo)
{
  __shared__ float s_mrg[4][16][8];   // [wave][row][{Z, t0..t5, pad2}]
  __shared__ float s_sw[16][4][6];    // [row][quarter][slot]
  __shared__ int   s_si[16][4][6];
  __shared__ int   s_cnt[16][4];

  // XCD-aware swizzle: 4 bh per XCD so Q/K/V splits stay L2-resident
  const int bid = blockIdx.x;
  const int bh  = ((bid & 7) << 2) | ((bid >> 3) >> 6);
  const int rowbase = ((bid >> 3) & 63) << 4;

  const int tid = threadIdx.x, lane = tid & 63, wvid = tid >> 6;
  const int l15 = lane & 15, l4 = lane >> 4;
  const size_t base = (size_t)bh << 16;
  const int kvbase = wvid << 8;

  // Q fragments (16 rows, live through both passes)
  bf16x8 qh8[2], ql8[2];
#pragma unroll
  for (int kf = 0; kf < 2; ++kf) {
    const size_t qa = base + (size_t)(rowbase + l15) * 64 + kf * 32 + l4 * 8;
    qh8[kf] = *(const bf16x8*)(qhh + qa);
    ql8[kf] = *(const bf16x8*)(qhl + qa);
  }
  const size_t k0 = base + (size_t)(kvbase + l15) * 64 + l4 * 8;

  // ---- pass 1: Z-sum + top-6 of raw scores, per (lane, ri) ----
  float t[4][6];
  float Zs[4] = {0.f, 0.f, 0.f, 0.f};
#pragma unroll
  for (int ri = 0; ri < 4; ++ri)
#pragma unroll
    for (int j = 0; j < 6; ++j) t[ri][j] = -3e38f;

  for (int kt = 0; kt < 16; ++kt) {
    const f32x4 acc = score_tile(qh8, ql8, khh, khl, k0 + (size_t)kt * 1024);
#pragma unroll
    for (int ri = 0; ri < 4; ++ri) {
      const float s = acc[ri];
      Zs[ri] += exp2f(s * CEXP);
      float v = s;
#pragma unroll
      for (int j = 0; j < 6; ++j) {
        const float a = fmaxf(t[ri][j], v);
        v = fminf(t[ri][j], v);
        t[ri][j] = a;
      }
    }
  }

  // ---- intra-wave merge across the 16 row-lanes (offsets 1,2,4,8) ----
#pragma unroll
  for (int ri = 0; ri < 4; ++ri) {
#pragma unroll
    for (int off = 1; off < 16; off <<= 1) Zs[ri] += __shfl_xor(Zs[ri], off);
#pragma unroll
    for (int off = 1; off < 16; off <<= 1) {
      float b[6];
#pragma unroll
      for (int j = 0; j < 6; ++j) b[j] = __shfl_xor(t[ri][j], off);
      merge6(t[ri], b);
    }
  }

  // ---- cross-wave merge via LDS ----
  if (l15 < 7) {
#pragma unroll
    for (int ri = 0; ri < 4; ++ri) {
      const float val = (l15 == 0) ? Zs[ri] :
                        (l15 == 1) ? t[ri][0] : (l15 == 2) ? t[ri][1] :
                        (l15 == 3) ? t[ri][2] : (l15 == 4) ? t[ri][3] :
                        (l15 == 5) ? t[ri][4] : t[ri][5];
      s_mrg[wvid][l4 * 4 + ri][l15] = val;
    }
  }
  __syncthreads();

  float u6x[4], inv[4];
#pragma unroll
  for (int ri = 0; ri < 4; ++ri) {
    const int row = l4 * 4 + ri;
    float m[6], Zt = 0.f;
#pragma unroll
    for (int w2 = 0; w2 < 4; ++w2) {
      const f32x4 pa = *(const f32x4*)&s_mrg[w2][row][0];
      const f32x4 pb = *(const f32x4*)&s_mrg[w2][row][4];
      Zt += pa[0];
      float b[6] = {pa[1], pa[2], pa[3], pb[0], pb[1], pb[2]};
      if (w2 == 0) {
#pragma unroll
        for (int j = 0; j < 6; ++j) m[j] = b[j];
      } else {
        merge6(m, b);
      }
    }
    const float Zx = SP_EPS * Zt;
    const float u6e = exp2f(m[5] * CEXP) + Zx;
    float Ss = 0.f;
    Ss += fmaxf(exp2f(m[0] * CEXP) - u6e, 0.f);
    Ss += fmaxf(exp2f(m[1] * CEXP) - u6e, 0.f);
    Ss += fmaxf(exp2f(m[2] * CEXP) - u6e, 0.f);
    Ss += fmaxf(exp2f(m[3] * CEXP) - u6e, 0.f);
    Ss += fmaxf(exp2f(m[4] * CEXP) - u6e, 0.f);
    u6x[ri] = u6e;
    inv[ri] = 1.0f / (Ss + Zx);
  }

  // ---- pass 2: recompute, full-row store, survivor collection ----
  int cnt[4] = {0, 0, 0, 0};
  float* arow = attn + ((size_t)bh << 20);
  for (int kt = 0; kt < 16; ++kt) {
    const f32x4 acc = score_tile(qh8, ql8, khh, khl, k0 + (size_t)kt * 1024);
    const int kvi = kvbase + kt * 16 + l15;
#pragma unroll
    for (int ri = 0; ri < 4; ++ri) {
      const float u = exp2f(acc[ri] * CEXP);
      const float wv = u - u6x[ri];
      const float aval = fmaxf(wv, 0.f) * inv[ri];
      arow[(size_t)(rowbase + l4 * 4 + ri) * 1024 + kvi] = aval;
      const unsigned long long msk = __ballot(wv > 0.f);
      const unsigned sub = (unsigned)(msk >> (l4 * 16)) & 0xFFFFu;
      if (wv > 0.f) {
        const int pos = cnt[ri] + __popc(sub & ((1u << l15) - 1u));
        if (pos < 6) {
          s_sw[l4 * 4 + ri][wvid][pos] = aval;
          s_si[l4 * 4 + ri][wvid][pos] = kvi;
        }
      }
      cnt[ri] += __popc(sub);
    }
  }
  if (l15 == 0) {
#pragma unroll
    for (int ri = 0; ri < 4; ++ri) s_cnt[l4 * 4 + ri][wvid] = min(cnt[ri], 6);
  }
  __syncthreads();

  // ---- PV + out_full split write: wave w handles rows 4w..4w+3, lane=dim --
  const float* vb = vh + base;
  const int b_ = bh & 3, h = bh >> 2;
#pragma unroll
  for (int rr = 0; rr < 4; ++rr) {
    const int row = (wvid << 2) | rr;
    float a = 0.f;
#pragma unroll
    for (int qw = 0; qw < 4; ++qw) {
      const int n = s_cnt[row][qw];
      for (int tt = 0; tt < n; ++tt)
        a = fmaf(s_sw[row][qw][tt], vb[(size_t)s_si[row][qw][tt] * 64 + lane], a);
    }
    const int lq = rowbase + row;
    const int oidx = (((b_ << 10) | lq) << 9) + (h << 6) + lane;
    const unsigned short hv = f2bf(a);
    ofhi[oidx] = hv;
    oflo[oidx] = f2bf(a - bf2f(hv));
  }
}

// ---------------- kernel 3: fc+gate via split-bf16 MFMA + fused epilogue ---
__global__ __launch_bounds__(256) void out_proj_mfma_kernel(
    const unsigned short* __restrict__ ofhi, const unsigned short* __restrict__ oflo,
    const unsigned short* __restrict__ FG,
    const float* __restrict__ bfc, const float* __restrict__ bg,
    float* __restrict__ out)
{
  __shared__ short Ash[64 * 64], Asl[64 * 64];
  __shared__ short Bfh[128 * 64], Bfl[128 * 64];
  __shared__ short Bgh[128 * 64], Bgl[128 * 64];
  const unsigned short* Wfh = FG;
  const unsigned short* Wfl = FG + (1u << 18);
  const unsigned short* Wgh = FG + (2u << 18);
  const unsigned short* Wgl = FG + 3u * (1u << 18);
  const int r0 = blockIdx.x * 64, n0 = blockIdx.y * 128;
  const int tid = threadIdx.x, lane = tid & 63, w = tid >> 6;
  const int wr = w >> 1, wc = w & 1;
  const int l15 = lane & 15, l4 = lane >> 4;

  f32x4 accf[2][4], accg[2][4];
#pragma unroll
  for (int a = 0; a < 2; ++a)
#pragma unroll
    for (int b = 0; b < 4; ++b) {
      accf[a][b] = (f32x4){0.f, 0.f, 0.f, 0.f};
      accg[a][b] = (f32x4){0.f, 0.f, 0.f, 0.f};
    }

  for (int kt = 0; kt < 8; ++kt) {
    __syncthreads();
#pragma unroll
    for (int p = 0; p < 2; ++p) {
      const int c = tid + p * 256, row = c >> 3, k8 = (c & 7) * 8;
      const size_t go = (size_t)(r0 + row) * 512 + kt * 64 + k8;
      const int si = row * 64 + (k8 ^ ((row & 7) << 3));
      *(bf16x8*)&Ash[si] = *(const bf16x8*)(ofhi + go);
      *(bf16x8*)&Asl[si] = *(const bf16x8*)(oflo + go);
    }
#pragma unroll
    for (int p = 0; p < 4; ++p) {
      const int c = tid + p * 256, row = c >> 3, k8 = (c & 7) * 8;
      const int si = row * 64 + (k8 ^ ((row & 7) << 3));
      const size_t go = (size_t)(n0 + row) * 512 + kt * 64 + k8;
      *(bf16x8*)&Bfh[si] = *(const bf16x8*)(Wfh + go);
      *(bf16x8*)&Bfl[si] = *(const bf16x8*)(Wfl + go);
      *(bf16x8*)&Bgh[si] = *(const bf16x8*)(Wgh + go);
      *(bf16x8*)&Bgl[si] = *(const bf16x8*)(Wgl + go);
    }
    __syncthreads();
#pragma unroll
    for (int kf = 0; kf < 2; ++kf) {
      const int kb = kf * 32 + l4 * 8;
      bf16x8 ah[2], al2[2];
#pragma unroll
      for (int rb = 0; rb < 2; ++rb) {
        const int ar = wr * 32 + rb * 16 + l15;
        const int si = ar * 64 + (kb ^ ((ar & 7) << 3));
        ah[rb] = *(bf16x8*)&Ash[si]; al2[rb] = *(bf16x8*)&Asl[si];
      }
#pragma unroll
      for (int cb = 0; cb < 4; ++cb) {
        const int br = wc * 64 + cb * 16 + l15;
        const int si = br * 64 + (kb ^ ((br & 7) << 3));
        const bf16x8 fh = *(bf16x8*)&Bfh[si];
        const bf16x8 fl = *(bf16x8*)&Bfl[si];
        const bf16x8 gh = *(bf16x8*)&Bgh[si];
        const bf16x8 gl = *(bf16x8*)&Bgl[si];
#pragma unroll
        for (int rb = 0; rb < 2; ++rb) {
          accf[rb][cb] = __builtin_amdgcn_mfma_f32_16x16x32_bf16(al2[rb], fh, accf[rb][cb], 0, 0, 0);
          accf[rb][cb] = __builtin_amdgcn_mfma_f32_16x16x32_bf16(ah[rb], fl, accf[rb][cb], 0, 0, 0);
          accf[rb][cb] = __builtin_amdgcn_mfma_f32_16x16x32_bf16(ah[rb], fh, accf[rb][cb], 0, 0, 0);
          accg[rb][cb] = __builtin_amdgcn_mfma_f32_16x16x32_bf16(al2[rb], gh, accg[rb][cb], 0, 0, 0);
          accg[rb][cb] = __builtin_amdgcn_mfma_f32_16x16x32_bf16(ah[rb], gl, accg[rb][cb], 0, 0, 0);
          accg[rb][cb] = __builtin_amdgcn_mfma_f32_16x16x32_bf16(ah[rb], gh, accg[rb][cb], 0, 0, 0);
        }
      }
    }
  }
#pragma unroll
  for (int cb = 0; cb < 4; ++cb) {
    const int col = n0 + wc * 64 + cb * 16 + l15;
    const float bf4 = bfc[col];
    const float bg4 = bg[col];
#pragma unroll
    for (int rb = 0; rb < 2; ++rb)
#pragma unroll
      for (int ri = 0; ri < 4; ++ri) {
        const int row = r0 + wr * 32 + rb * 16 + l4 * 4 + ri;
        const float f = accf[rb][cb][ri] + bf4;
        const float g = accg[rb][cb][ri] + bg4;
        out[(size_t)row * 512 + col] = tanhf(f) / (1.f + __expf(-g));
      }
  }
}

extern "C" void kernel_launch(void* const* d_in, const int* in_sizes, int n_in,
                              void* d_out, int out_size, void* d_ws, size_t ws_size,
                              hipStream_t stream) {
  const float* q   = (const float*)d_in[0];
  const float* k   = (const float*)d_in[1];
  const float* v   = (const float*)d_in[2];
  const float* Wq  = (const float*)d_in[3];
  const float* bq  = (const float*)d_in[4];
  const float* Wk  = (const float*)d_in[5];
  const float* bk  = (const float*)d_in[6];
  const float* Wv  = (const float*)d_in[7];
  const float* bv  = (const float*)d_in[8];
  const float* Wfc = (const float*)d_in[9];
  const float* bfc = (const float*)d_in[10];
  const float* Wg  = (const float*)d_in[11];
  const float* bg  = (const float*)d_in[12];

  float* out  = (float*)d_out;
  float* attn = out + OUT0;                 // (32,1024,1024) final output 1

  // qh splits live in the out0 region (8MB, overwritten by out_proj at the end)
  unsigned short* qhh = (unsigned short*)d_out;
  unsigned short* qhl = qhh + (1u << 21);

  // ws (24MB): [0,8M) khh/khl -> later FG; [8,16M) vh; [16M..) Wqkv -> ofhi/oflo
  char* wsb = (char*)d_ws;
  unsigned short* khh  = (unsigned short*)wsb;
  unsigned short* khl  = (unsigned short*)(wsb + (4u << 20));
  float*          vh   = (float*)(wsb + (8u << 20));
  unsigned short* Wqkv = (unsigned short*)(wsb + (16u << 20));
  unsigned short* ofhi = (unsigned short*)(wsb + (16u << 20));
  unsigned short* oflo = (unsigned short*)(wsb + (20u << 20));
  unsigned short* FG   = (unsigned short*)wsb;

  convW_kernel<<<dim3(256, 1, 3), 256, 0, stream>>>(Wq, Wk, Wv, Wqkv);
  qkv_mfma_kernel<<<dim3(64, 4, 3), 256, 0, stream>>>(q, k, v, Wqkv, bq, bk, bv,
                                                      qhh, qhl, khh, khl, vh);
  sparse_attn_kernel<<<dim3(2048), 256, 0, stream>>>(qhh, qhl, khh, khl, vh,
                                                     attn, ofhi, oflo);
  convW_kernel<<<dim3(256, 1, 2), 256, 0, stream>>>(Wfc, Wg, Wg, FG);
  out_proj_mfma_kernel<<<dim3(64, 4), 256, 0, stream>>>(ofhi, oflo, FG, bfc, bg, out);
}